// Round 5
// baseline (25625.565 us; speedup 1.0000x reference)
//
#include <hip/hip_runtime.h>

#define NB 64      // batch
#define NS 512     // seq len
#define NE 512     // emb dim
#define NH 512     // per-dir hidden
#define NG 2048    // 4*NH
#define NT 64      // tags
#define KC 1024    // combined K = NE + NH
#define HB 16777216   // u16 elements per direction in HALL: 512*64*512
#define SENT32 0x7FC07FC0u  // bf16 NaN|NaN — unreachable for h
#define NEGV (-10000.0f)

typedef __attribute__((ext_vector_type(8))) short bf16x8;
typedef __attribute__((ext_vector_type(4))) float f32x4;
typedef unsigned short u16;
typedef unsigned int u32;
typedef unsigned long long u64;

__device__ __forceinline__ u16 f2bf(float x) {
    unsigned u = __builtin_bit_cast(unsigned, x);
    u += 0x7fffu + ((u >> 16) & 1u);
    return (u16)(u >> 16);
}
// fast sigmoid/tanh via v_exp_f32 + v_rcp_f32 (~1e-3 rel err, far inside tolerance)
__device__ __forceinline__ float sig_(float x) {
    return __builtin_amdgcn_rcpf(1.0f + __builtin_amdgcn_exp2f(-1.44269504f * x));
}
__device__ __forceinline__ float tanh_(float x) {
    return 2.0f * __builtin_amdgcn_rcpf(1.0f + __builtin_amdgcn_exp2f(-2.88539009f * x)) - 1.0f;
}

// ---------- prep: combined [W_ih | W_hh] -> bf16, [2][2048][1024] ----------
__global__ void prep_wcomb(const float* __restrict__ wihf, const float* __restrict__ whhf,
                           const float* __restrict__ wihb, const float* __restrict__ whhb,
                           u16* __restrict__ wcomb) {
    int idx = blockIdx.x * 256 + threadIdx.x;   // 1,048,576 threads, 4 elems each
    int base = idx * 4;
    int d = base >> 21;
    int rem = base & ((1 << 21) - 1);
    int n = rem >> 10;
    int k = rem & 1023;
    const float* wih = d ? wihb : wihf;
    const float* whh = d ? whhb : whhf;
    const float* src = (k < NE) ? (wih + n * NE + k) : (whh + n * NH + (k - NE));
    float4 v = *reinterpret_cast<const float4*>(src);
    ushort4 o;
    o.x = f2bf(v.x); o.y = f2bf(v.y); o.z = f2bf(v.z); o.w = f2bf(v.w);
    *reinterpret_cast<ushort4*>(wcomb + base) = o;
}

// ---------- prep: w_out->bf16, bias = b_ih+b_hh ----------
__global__ void prep_misc(const float* __restrict__ wout,
                          const float* __restrict__ bihf, const float* __restrict__ bhhf,
                          const float* __restrict__ bihb, const float* __restrict__ bhhb,
                          u16* __restrict__ woutbf, float* __restrict__ bias) {
    int idx = blockIdx.x * 256 + threadIdx.x;   // 272 blocks = 69,632 threads
    if (idx < 65536) { woutbf[idx] = f2bf(wout[idx]); return; }
    idx -= 65536;
    if (idx < 4096) {
        int d = idx >> 11, g = idx & 2047;
        bias[idx] = d ? (bihb[g] + bhhb[g]) : (bihf[g] + bhhf[g]);
    }
}

// ---------- prep: sentinel-fill HALL (64 MiB) ----------
__global__ void prep_hfill(uint4* __restrict__ h) {
    int idx = blockIdx.x * 256 + threadIdx.x;   // 16384 blocks
    uint4 v = {SENT32, SENT32, SENT32, SENT32};
    h[idx] = v;
}

// ---------- prep: embedding gather -> x_bf[(s*64+b)][512] bf16 ----------
__global__ void prep_embed(const float* __restrict__ emb, const int* __restrict__ sents,
                           u16* __restrict__ xbf) {
    int idx = blockIdx.x * 256 + threadIdx.x;   // 4,194,304 threads, 4 elems each
    int m = idx >> 7;
    int e = (idx & 127) << 2;
    int s = m >> 6, b = m & 63;
    int tok = sents[b * NS + s];
    float4 v = *reinterpret_cast<const float4*>(emb + (size_t)tok * NE + e);
    ushort4 o;
    o.x = f2bf(v.x); o.y = f2bf(v.y); o.z = f2bf(v.z); o.w = f2bf(v.w);
    *reinterpret_cast<ushort4*>(xbf + (size_t)m * NE + e) = o;
}

// ---------- persistent bi-LSTM: grid (32 jblk, 2 dir), 512 thr ----------
// HALL per dir: row-major h[s][b][j] bf16. Producers publish h via relaxed
// agent-scope (coherence-point) stores; consumers sentinel-poll the data
// itself in TWO load groups per step (one wait each). One barrier per step.
__global__ __launch_bounds__(512, 1)
void lstm_persist(const u16* __restrict__ xbf, const u16* __restrict__ wcomb,
                  const float* __restrict__ bias, u16* __restrict__ hall) {
    const int jblk = blockIdx.x;   // 0..31 -> j slice of 16
    const int dir  = blockIdx.y;   // 0 fwd, 1 bwd
    const int t = threadIdx.x;
    const int w = t >> 6, l = t & 63;
    const int l16 = l & 15, lhi = l >> 4;
    const int kw = w & 3;          // K-slice of 256
    const int nh = w >> 2;         // gate-half: 0 -> i,f ; 1 -> g,o
    const int kbase = kw * 256;
    const bool isx = (kw < 2);

    __shared__ float gred[2][4][64][68];   // 136 KiB, parity double-buffered

    // ---- B-fragments in registers (once): 2 n-frags x 8 k-tiles = 64 VGPR ----
    bf16x8 bfrag[2][8];
#pragma unroll
    for (int nf = 0; nf < 2; ++nf)
#pragma unroll
        for (int kt = 0; kt < 8; ++kt) {
            int gr = (nh * 2 + nf) * NH + jblk * 16 + l16;
            int k = kbase + kt * 32 + lhi * 8;
            bfrag[nf][kt] = *reinterpret_cast<const bf16x8*>(
                wcomb + (size_t)(dir * NG + gr) * KC + k);
        }

    // ---- epilogue ownership: thread -> (bb = t>>3, j pair jc = (t&7)*2) ----
    const int bb = t >> 3;
    const int jc = (t & 7) * 2;
    float breg[4][2];
#pragma unroll
    for (int gi = 0; gi < 4; ++gi)
#pragma unroll
        for (int u = 0; u < 2; ++u)
            breg[gi][u] = bias[dir * NG + gi * NH + jblk * 16 + jc + u];
    float c0 = 0.f, c1 = 0.f;

    u32* Hw = reinterpret_cast<u32*>(hall) + (size_t)dir * (HB / 2);
    const u64* Hq = reinterpret_cast<const u64*>(hall) + (size_t)dir * (HB / 4);

    for (int step = 0; step < NS; ++step) {
        const int s = dir ? (NS - 1 - step) : step;
        const int sprev = dir ? (s + 1) : (s - 1);
        const int par = step & 1;

        f32x4 acc[4][2];
#pragma unroll
        for (int mf = 0; mf < 4; ++mf)
#pragma unroll
            for (int nf = 0; nf < 2; ++nf)
                acc[mf][nf] = (f32x4){0.f, 0.f, 0.f, 0.f};

        if (isx) {
            // x part: no cross-block dependency -> never waits
            const u16* Abase = xbf + (size_t)(s * NB) * NE + kbase;
#pragma unroll
            for (int kt = 0; kt < 8; ++kt) {
                int k = kt * 32 + lhi * 8;
#pragma unroll
                for (int mf = 0; mf < 4; ++mf) {
                    bf16x8 a = *reinterpret_cast<const bf16x8*>(Abase + (size_t)(mf * 16 + l16) * NE + k);
                    acc[mf][0] = __builtin_amdgcn_mfma_f32_16x16x32_bf16(a, bfrag[0][kt], acc[mf][0], 0, 0, 0);
                    acc[mf][1] = __builtin_amdgcn_mfma_f32_16x16x32_bf16(a, bfrag[1][kt], acc[mf][1], 0, 0, 0);
                }
            }
        } else if (step > 0) {
            const int kloc = kbase - 512;
            // two load groups; ONE wait point per group
#pragma unroll
            for (int kg = 0; kg < 2; ++kg) {
                u64 dq[4][4][2];
                for (;;) {
                    u32 bad = 0;
#pragma unroll
                    for (int k2 = 0; k2 < 4; ++k2) {
                        int j0 = kloc + (kg * 4 + k2) * 32 + lhi * 8;
                        const u64* P = Hq + (size_t)(sprev * NB) * 128 + (j0 >> 2);
#pragma unroll
                        for (int mf = 0; mf < 4; ++mf) {
                            u64 v0 = __hip_atomic_load(P + (size_t)(mf * 16 + l16) * 128,
                                                       __ATOMIC_RELAXED, __HIP_MEMORY_SCOPE_AGENT);
                            u64 v1 = __hip_atomic_load(P + (size_t)(mf * 16 + l16) * 128 + 1,
                                                       __ATOMIC_RELAXED, __HIP_MEMORY_SCOPE_AGENT);
                            dq[k2][mf][0] = v0; dq[k2][mf][1] = v1;
                            bad |= (u32)((u32)v0 == SENT32) | (u32)((u32)(v0 >> 32) == SENT32)
                                 | (u32)((u32)v1 == SENT32) | (u32)((u32)(v1 >> 32) == SENT32);
                        }
                    }
                    if (!__ballot(bad)) break;
                }
#pragma unroll
                for (int k2 = 0; k2 < 4; ++k2) {
#pragma unroll
                    for (int mf = 0; mf < 4; ++mf) {
                        union { u64 q[2]; bf16x8 v; } cv;
                        cv.q[0] = dq[k2][mf][0]; cv.q[1] = dq[k2][mf][1];
                        acc[mf][0] = __builtin_amdgcn_mfma_f32_16x16x32_bf16(cv.v, bfrag[0][kg * 4 + k2], acc[mf][0], 0, 0, 0);
                        acc[mf][1] = __builtin_amdgcn_mfma_f32_16x16x32_bf16(cv.v, bfrag[1][kg * 4 + k2], acc[mf][1], 0, 0, 0);
                    }
                }
            }
        }

        // ---- dump partials (parity buffer) ----
#pragma unroll
        for (int mf = 0; mf < 4; ++mf)
#pragma unroll
            for (int nf = 0; nf < 2; ++nf)
#pragma unroll
                for (int r = 0; r < 4; ++r)
                    gred[par][kw][mf * 16 + lhi * 4 + r][nh * 32 + nf * 16 + l16] = acc[mf][nf][r];
        __syncthreads();   // the ONLY barrier per step

        // ---- reduce K-partials + cell update (c in regs), 2 cells/thread ----
        float g[2][4];
#pragma unroll
        for (int u = 0; u < 2; ++u)
#pragma unroll
            for (int gi = 0; gi < 4; ++gi) {
                int n = gi * 16 + jc + u;
                g[u][gi] = gred[par][0][bb][n] + gred[par][1][bb][n]
                         + gred[par][2][bb][n] + gred[par][3][bb][n] + breg[gi][u];
            }
        float cn0 = sig_(g[0][1]) * c0 + sig_(g[0][0]) * tanh_(g[0][2]);
        float cn1 = sig_(g[1][1]) * c1 + sig_(g[1][0]) * tanh_(g[1][2]);
        c0 = cn0; c1 = cn1;
        u32 hw = (u32)f2bf(sig_(g[0][3]) * tanh_(cn0))
               | ((u32)f2bf(sig_(g[1][3]) * tanh_(cn1)) << 16);
        // fire-and-forget publish: h[s][bb][jblk*16 + jc]
        __hip_atomic_store(Hw + (size_t)(s * NB + bb) * 256 + jblk * 8 + (t & 7), hw,
                           __ATOMIC_RELAXED, __HIP_MEMORY_SCOPE_AGENT);
    }
}

// ---------- emissions: one block per s; rows b=0..63 ----------
__global__ void emis_kernel(const u16* __restrict__ hall, const u16* __restrict__ woutbf,
                            const float* __restrict__ bout, float* __restrict__ emis) {
    const int blk = blockIdx.x;                   // = s, 512 blocks
    const int t = threadIdx.x;
    const int w = t >> 6, l = t & 63;
    const int l16 = l & 15, lhi = l >> 4;

    const u16* arow0 = hall + (size_t)(blk * 64 + w * 16 + l16) * NH;
    const u16* arow1 = arow0 + HB;
    const u16* br0 = woutbf + (size_t)(0 * 16 + l16) * KC;
    const u16* br1 = woutbf + (size_t)(1 * 16 + l16) * KC;
    const u16* br2 = woutbf + (size_t)(2 * 16 + l16) * KC;
    const u16* br3 = woutbf + (size_t)(3 * 16 + l16) * KC;

    f32x4 a0 = {0.f,0.f,0.f,0.f}, a1 = {0.f,0.f,0.f,0.f}, a2 = {0.f,0.f,0.f,0.f}, a3 = {0.f,0.f,0.f,0.f};
#pragma unroll
    for (int kt = 0; kt < 16; ++kt) {             // h_f part
        int k = kt * 32 + lhi * 8;
        bf16x8 a = *reinterpret_cast<const bf16x8*>(arow0 + k);
        a0 = __builtin_amdgcn_mfma_f32_16x16x32_bf16(a, *reinterpret_cast<const bf16x8*>(br0 + k), a0, 0, 0, 0);
        a1 = __builtin_amdgcn_mfma_f32_16x16x32_bf16(a, *reinterpret_cast<const bf16x8*>(br1 + k), a1, 0, 0, 0);
        a2 = __builtin_amdgcn_mfma_f32_16x16x32_bf16(a, *reinterpret_cast<const bf16x8*>(br2 + k), a2, 0, 0, 0);
        a3 = __builtin_amdgcn_mfma_f32_16x16x32_bf16(a, *reinterpret_cast<const bf16x8*>(br3 + k), a3, 0, 0, 0);
    }
#pragma unroll
    for (int kt = 0; kt < 16; ++kt) {             // h_b part
        int k = kt * 32 + lhi * 8;
        bf16x8 a = *reinterpret_cast<const bf16x8*>(arow1 + k);
        a0 = __builtin_amdgcn_mfma_f32_16x16x32_bf16(a, *reinterpret_cast<const bf16x8*>(br0 + NH + k), a0, 0, 0, 0);
        a1 = __builtin_amdgcn_mfma_f32_16x16x32_bf16(a, *reinterpret_cast<const bf16x8*>(br1 + NH + k), a1, 0, 0, 0);
        a2 = __builtin_amdgcn_mfma_f32_16x16x32_bf16(a, *reinterpret_cast<const bf16x8*>(br2 + NH + k), a2, 0, 0, 0);
        a3 = __builtin_amdgcn_mfma_f32_16x16x32_bf16(a, *reinterpret_cast<const bf16x8*>(br3 + NH + k), a3, 0, 0, 0);
    }
#pragma unroll
    for (int r = 0; r < 4; ++r) {
        int gm = blk * 64 + w * 16 + lhi * 4 + r;
        emis[(size_t)gm * NT + 0 * 16 + l16] = a0[r] + bout[0 * 16 + l16];
        emis[(size_t)gm * NT + 1 * 16 + l16] = a1[r] + bout[1 * 16 + l16];
        emis[(size_t)gm * NT + 2 * 16 + l16] = a2[r] + bout[2 * 16 + l16];
        emis[(size_t)gm * NT + 3 * 16 + l16] = a3[r] + bout[3 * 16 + l16];
    }
}

// ---------- gold score per batch ----------
__global__ void gold_kernel(const float* __restrict__ emis, const int* __restrict__ tags,
                            const float* __restrict__ trans, float* __restrict__ gold) {
    int b = blockIdx.x, t = threadIdx.x;
    float acc = 0.f;
    for (int s = t; s < NS; s += 256) {
        int tag = tags[b * NS + s];
        int prev = (s == 0) ? 0 : tags[b * NS + s - 1];
        acc += emis[(size_t)(s * NB + b) * NT + tag] + trans[tag * NT + prev];
    }
    acc += __shfl_xor(acc, 1);  acc += __shfl_xor(acc, 2);  acc += __shfl_xor(acc, 4);
    acc += __shfl_xor(acc, 8);  acc += __shfl_xor(acc, 16); acc += __shfl_xor(acc, 32);
    __shared__ float red[4];
    if ((t & 63) == 0) red[t >> 6] = acc;
    __syncthreads();
    if (t == 0) gold[b] = red[0] + red[1] + red[2] + red[3];
}

// ---------- CRF forward (log partition) per batch ----------
__global__ void crf_kernel(const float* __restrict__ emis, const float* __restrict__ trans,
                           float* __restrict__ fwd) {
    int b = blockIdx.x, t = threadIdx.x;
    __shared__ float transT[64][65];   // [prev][next]
    __shared__ float alA[64], alB[64];
    for (int idx = t; idx < 4096; idx += 256) {
        int next = idx & 63, prev = idx >> 6;
        transT[prev][next] = trans[next * NT + prev];
    }
    if (t < 64) alA[t] = (t == 0) ? 0.f : NEGV;
    __syncthreads();

    int next = t >> 2, q = t & 3;
    float* cur = alA;
    float* nxt = alB;
    for (int s = 0; s < NS; ++s) {
        float emit = emis[(size_t)(s * NB + b) * NT + next];
        int p0 = q * 16;
        float M = -3.0e38f;
#pragma unroll
        for (int i = 0; i < 16; ++i) {
            float v = cur[p0 + i] + transT[p0 + i][next];
            M = fmaxf(M, v);
        }
        M = fmaxf(M, __shfl_xor(M, 1));
        M = fmaxf(M, __shfl_xor(M, 2));
        float Ssum = 0.f;
#pragma unroll
        for (int i = 0; i < 16; ++i) {
            float v = cur[p0 + i] + transT[p0 + i][next];
            Ssum += expf(v - M);
        }
        Ssum += __shfl_xor(Ssum, 1);
        Ssum += __shfl_xor(Ssum, 2);
        if (q == 0) nxt[next] = M + logf(Ssum) + emit;
        __syncthreads();
        float* tmp = cur; cur = nxt; nxt = tmp;
    }
    if (t < 64) {
        float v = cur[t];
        float M = v;
        for (int d = 1; d < 64; d <<= 1) M = fmaxf(M, __shfl_xor(M, d));
        float e = expf(v - M);
        for (int d = 1; d < 64; d <<= 1) e += __shfl_xor(e, d);
        if (t == 0) fwd[b] = M + logf(e);
    }
}

// ---------- final: mean(fwd - gold) ----------
__global__ void final_kernel(const float* __restrict__ fwd, const float* __restrict__ gold,
                             float* __restrict__ out) {
    int t = threadIdx.x;   // 64
    float v = fwd[t] - gold[t];
    for (int d = 1; d < 64; d <<= 1) v += __shfl_xor(v, d);
    if (t == 0) out[0] = v * (1.0f / 64.0f);
}

extern "C" void kernel_launch(void* const* d_in, const int* in_sizes, int n_in,
                              void* d_out, int out_size, void* d_ws, size_t ws_size,
                              hipStream_t stream) {
    (void)in_sizes; (void)n_in; (void)out_size; (void)ws_size;
    const int* sents = (const int*)d_in[0];
    const int* tags  = (const int*)d_in[1];
    const float* emb  = (const float*)d_in[3];
    const float* wihf = (const float*)d_in[4];
    const float* whhf = (const float*)d_in[5];
    const float* bihf = (const float*)d_in[6];
    const float* bhhf = (const float*)d_in[7];
    const float* wihb = (const float*)d_in[8];
    const float* whhb = (const float*)d_in[9];
    const float* bihb = (const float*)d_in[10];
    const float* bhhb = (const float*)d_in[11];
    const float* wout = (const float*)d_in[12];
    const float* bout = (const float*)d_in[13];
    const float* trans = (const float*)d_in[14];

    char* ws = (char*)d_ws;
    u16*   WCOMB  = (u16*)(ws + 0);              //  8 MiB  [2][2048][1024] bf16
    u16*   WOUTBF = (u16*)(ws + 8388608);        //  128 KiB [64][1024] bf16
    float* BIAS   = (float*)(ws + 8519680);      //  16 KiB  [2][2048] f32
    u16*   XBF    = (u16*)(ws + 8536064);        //  32 MiB  [32768][512] bf16
    u16*   HALL   = (u16*)(ws + 42090496);       //  64 MiB  [2][512][64][512] bf16
    float* EMIS   = (float*)(ws + 109199360);    //  8 MiB   [512*64][64] f32
    float* FWD    = (float*)(ws + 117587968);    //  [64] f32
    float* GOLD   = (float*)(ws + 117588224);    //  [64] f32

    prep_wcomb<<<4096, 256, 0, stream>>>(wihf, whhf, wihb, whhb, WCOMB);
    prep_misc<<<272, 256, 0, stream>>>(wout, bihf, bhhf, bihb, bhhb, WOUTBF, BIAS);
    prep_hfill<<<16384, 256, 0, stream>>>((uint4*)HALL);
    prep_embed<<<16384, 256, 0, stream>>>(emb, sents, XBF);

    lstm_persist<<<dim3(32, 2), 512, 0, stream>>>(XBF, WCOMB, BIAS, HALL);

    emis_kernel<<<512, 256, 0, stream>>>(HALL, WOUTBF, bout, EMIS);
    gold_kernel<<<64, 256, 0, stream>>>(EMIS, tags, trans, GOLD);
    crf_kernel<<<64, 256, 0, stream>>>(EMIS, trans, FWD);
    final_kernel<<<1, 64, 0, stream>>>(FWD, GOLD, (float*)d_out);
}

// Round 6
// 4712.725 us; speedup vs baseline: 5.4375x; 5.4375x over previous
//
#include <hip/hip_runtime.h>

#define NB 64      // batch
#define NS 512     // seq len
#define NE 512     // emb dim
#define NH 512     // per-dir hidden
#define NG 2048    // 4*NH
#define NT 64      // tags
#define KC 1024    // combined K = NE + NH
#define HB 16777216   // u16 elements per direction in HALL
#define NEGV (-10000.0f)

typedef __attribute__((ext_vector_type(8))) short bf16x8;
typedef __attribute__((ext_vector_type(4))) float f32x4;
typedef unsigned short u16;
typedef unsigned int u32;
typedef unsigned long long u64;

__device__ __forceinline__ u16 f2bf(float x) {
    unsigned u = __builtin_bit_cast(unsigned, x);
    u += 0x7fffu + ((u >> 16) & 1u);
    return (u16)(u >> 16);
}
__device__ __forceinline__ float sig_(float x) {
    return __builtin_amdgcn_rcpf(1.0f + __builtin_amdgcn_exp2f(-1.44269504f * x));
}
__device__ __forceinline__ float tanh_(float x) {
    return 2.0f * __builtin_amdgcn_rcpf(1.0f + __builtin_amdgcn_exp2f(-2.88539009f * x)) - 1.0f;
}

// ---------- prep: combined [W_ih | W_hh] -> bf16, [2][2048][1024] ----------
__global__ void prep_wcomb(const float* __restrict__ wihf, const float* __restrict__ whhf,
                           const float* __restrict__ wihb, const float* __restrict__ whhb,
                           u16* __restrict__ wcomb) {
    int idx = blockIdx.x * 256 + threadIdx.x;   // 1,048,576 threads, 4 elems each
    int base = idx * 4;
    int d = base >> 21;
    int rem = base & ((1 << 21) - 1);
    int n = rem >> 10;
    int k = rem & 1023;
    const float* wih = d ? wihb : wihf;
    const float* whh = d ? whhb : whhf;
    const float* src = (k < NE) ? (wih + n * NE + k) : (whh + n * NH + (k - NE));
    float4 v = *reinterpret_cast<const float4*>(src);
    ushort4 o;
    o.x = f2bf(v.x); o.y = f2bf(v.y); o.z = f2bf(v.z); o.w = f2bf(v.w);
    *reinterpret_cast<ushort4*>(wcomb + base) = o;
}

// ---------- prep: w_out->bf16, bias = b_ih+b_hh, flags = 0 ----------
__global__ void prep_misc(const float* __restrict__ wout,
                          const float* __restrict__ bihf, const float* __restrict__ bhhf,
                          const float* __restrict__ bihb, const float* __restrict__ bhhb,
                          u16* __restrict__ woutbf, float* __restrict__ bias,
                          u32* __restrict__ flags) {
    int idx = blockIdx.x * 256 + threadIdx.x;   // 274 blocks = 70,144 threads
    if (idx < 65536) { woutbf[idx] = f2bf(wout[idx]); return; }
    idx -= 65536;
    if (idx < 4096) {
        int d = idx >> 11, g = idx & 2047;
        bias[idx] = d ? (bihb[g] + bhhb[g]) : (bihf[g] + bhhf[g]);
        return;
    }
    idx -= 4096;
    if (idx < 512) flags[idx] = 0;
}

// ---------- prep: embedding gather -> x_bf[(s*64+b)][512] bf16 ----------
__global__ void prep_embed(const float* __restrict__ emb, const int* __restrict__ sents,
                           u16* __restrict__ xbf) {
    int idx = blockIdx.x * 256 + threadIdx.x;   // 4,194,304 threads, 4 elems each
    int m = idx >> 7;
    int e = (idx & 127) << 2;
    int s = m >> 6, b = m & 63;
    int tok = sents[b * NS + s];
    float4 v = *reinterpret_cast<const float4*>(emb + (size_t)tok * NE + e);
    ushort4 o;
    o.x = f2bf(v.x); o.y = f2bf(v.y); o.z = f2bf(v.z); o.w = f2bf(v.w);
    *reinterpret_cast<ushort4*>(xbf + (size_t)m * NE + e) = o;
}

// ---------- persistent bi-LSTM: grid (64 jblk, 2 dir), 256 thr, 4 waves ----------
// HALL u32 view: [dir][s][jblk(64)][bb(64)][p(4)].  Per-PRODUCER-WAVE flags
// (256/dir): wave drains its own h stores (s_waitcnt vmcnt(0)) then lane0
// publishes flag=step+1.  Consumers poll all 256 flags packed: 64 lanes x
// 2 u64 sc-loads = 1 KB, one L3 round trip per poll iteration.  Data loads
// happen exactly once after flags confirm.  ONE barrier per step (parity gred).
__global__ __launch_bounds__(256, 1)
void lstm_persist(const u16* __restrict__ xbf, const u16* __restrict__ wcomb,
                  const float* __restrict__ bias, u16* __restrict__ hall,
                  u32* __restrict__ flags) {
    const int jblk = blockIdx.x;   // 0..63 -> j slice of 8
    const int dir  = blockIdx.y;   // 0 fwd, 1 bwd
    const int t = threadIdx.x;
    const int w = t >> 6, l = t & 63;
    const int l16 = l & 15, lhi = l >> 4;

    __shared__ u16 wlds[64 * 64 * 8];        // 64 KiB: [slot=w*16+kt*2+nf][lane][8]
    __shared__ float gred[2][4][64][33];     // 66 KiB, parity double-buffered

    // ---- stage weights into LDS (once) ----
    for (int slot = w; slot < 64; slot += 4) {
        int ww = slot >> 4, kt = (slot >> 1) & 7, nf = slot & 1;
        int n = nf * 16 + l16;
        int gr = (n >> 3) * NH + jblk * 8 + (n & 7);
        int k = ww * 256 + kt * 32 + lhi * 8;
        bf16x8 v = *reinterpret_cast<const bf16x8*>(wcomb + (size_t)(dir * NG + gr) * KC + k);
        *reinterpret_cast<bf16x8*>(wlds + (size_t)(slot * 64 + l) * 8) = v;
    }

    // ---- epilogue ownership: thread -> (bb = t>>2, word p = t&3, jj = 2p) ----
    const int bb = t >> 2;
    const int p  = t & 3;
    const int jj = p * 2;
    float breg[4][2];
#pragma unroll
    for (int gi = 0; gi < 4; ++gi)
#pragma unroll
        for (int u = 0; u < 2; ++u)
            breg[gi][u] = bias[dir * NG + gi * NH + jblk * 8 + jj + u];
    float c0 = 0.f, c1 = 0.f;    // cell state in registers

    const int kbase = w * 256;
    const bool isx = (w < 2);
    u32* Hw = reinterpret_cast<u32*>(hall) + (size_t)dir * (HB / 2);
    const u64* Hq = reinterpret_cast<const u64*>(hall) + (size_t)dir * (HB / 4);
    u32* myflag = flags + dir * 256 + jblk * 4 + w;
    const u64* FQ = reinterpret_cast<const u64*>(flags + dir * 256);
    __syncthreads();

    for (int step = 0; step < NS; ++step) {
        const int s = dir ? (NS - 1 - step) : step;
        const int sprev = dir ? (s + 1) : (s - 1);
        const int par = step & 1;

        f32x4 acc[4][2];
#pragma unroll
        for (int mf = 0; mf < 4; ++mf)
#pragma unroll
            for (int nf = 0; nf < 2; ++nf)
                acc[mf][nf] = (f32x4){0.f, 0.f, 0.f, 0.f};

        if (isx) {
            // x part: no cross-block dependency -> never waits
            const u16* Abase = xbf + (size_t)(s * NB) * NE + kbase;
#pragma unroll
            for (int kt = 0; kt < 8; ++kt) {
                bf16x8 b0 = *reinterpret_cast<const bf16x8*>(wlds + (size_t)((w * 16 + kt * 2 + 0) * 64 + l) * 8);
                bf16x8 b1 = *reinterpret_cast<const bf16x8*>(wlds + (size_t)((w * 16 + kt * 2 + 1) * 64 + l) * 8);
                int k = kt * 32 + lhi * 8;
#pragma unroll
                for (int mf = 0; mf < 4; ++mf) {
                    bf16x8 a = *reinterpret_cast<const bf16x8*>(Abase + (size_t)(mf * 16 + l16) * NE + k);
                    acc[mf][0] = __builtin_amdgcn_mfma_f32_16x16x32_bf16(a, b0, acc[mf][0], 0, 0, 0);
                    acc[mf][1] = __builtin_amdgcn_mfma_f32_16x16x32_bf16(a, b1, acc[mf][1], 0, 0, 0);
                }
            }
        } else if (step > 0) {
            // ---- packed flag poll: lane l covers producer waves 4l..4l+3 ----
            const u32 want = (u32)step;
            for (;;) {
                u64 v0 = __hip_atomic_load(FQ + l * 2,     __ATOMIC_RELAXED, __HIP_MEMORY_SCOPE_AGENT);
                u64 v1 = __hip_atomic_load(FQ + l * 2 + 1, __ATOMIC_RELAXED, __HIP_MEMORY_SCOPE_AGENT);
                bool ok = ((u32)v0 >= want) & ((u32)(v0 >> 32) >= want)
                        & ((u32)v1 >= want) & ((u32)(v1 >> 32) >= want);
                if (!__ballot(!ok)) break;
            }
            __builtin_amdgcn_sched_barrier(0);

            // ---- data loads: exactly once, all 32 fragments ----
            const int kloc = kbase - 512;
            bf16x8 afrag[8][4];
#pragma unroll
            for (int kt = 0; kt < 8; ++kt) {
                int chunk = (kloc + kt * 32 + lhi * 8) >> 3;
                const u64* P = Hq + (size_t)(sprev * 64 + chunk) * 128;
#pragma unroll
                for (int mf = 0; mf < 4; ++mf) {
                    union { u64 q[2]; bf16x8 v; } cv;
                    cv.q[0] = __hip_atomic_load(P + (size_t)(mf * 16 + l16) * 2,
                                                __ATOMIC_RELAXED, __HIP_MEMORY_SCOPE_AGENT);
                    cv.q[1] = __hip_atomic_load(P + (size_t)(mf * 16 + l16) * 2 + 1,
                                                __ATOMIC_RELAXED, __HIP_MEMORY_SCOPE_AGENT);
                    afrag[kt][mf] = cv.v;
                }
            }
#pragma unroll
            for (int kt = 0; kt < 8; ++kt) {
                bf16x8 b0 = *reinterpret_cast<const bf16x8*>(wlds + (size_t)((w * 16 + kt * 2 + 0) * 64 + l) * 8);
                bf16x8 b1 = *reinterpret_cast<const bf16x8*>(wlds + (size_t)((w * 16 + kt * 2 + 1) * 64 + l) * 8);
#pragma unroll
                for (int mf = 0; mf < 4; ++mf) {
                    acc[mf][0] = __builtin_amdgcn_mfma_f32_16x16x32_bf16(afrag[kt][mf], b0, acc[mf][0], 0, 0, 0);
                    acc[mf][1] = __builtin_amdgcn_mfma_f32_16x16x32_bf16(afrag[kt][mf], b1, acc[mf][1], 0, 0, 0);
                }
            }
        }

        // ---- dump partials (parity buffer) ----
#pragma unroll
        for (int mf = 0; mf < 4; ++mf)
#pragma unroll
            for (int nf = 0; nf < 2; ++nf)
#pragma unroll
                for (int r = 0; r < 4; ++r)
                    gred[par][w][mf * 16 + lhi * 4 + r][nf * 16 + l16] = acc[mf][nf][r];
        __syncthreads();   // the ONLY barrier per step

        // ---- reduce K-partials + cell update (c in regs) ----
        float g[2][4];
#pragma unroll
        for (int u = 0; u < 2; ++u)
#pragma unroll
            for (int gi = 0; gi < 4; ++gi) {
                int n = gi * 8 + jj + u;
                g[u][gi] = gred[par][0][bb][n] + gred[par][1][bb][n]
                         + gred[par][2][bb][n] + gred[par][3][bb][n] + breg[gi][u];
            }
        float cn0 = sig_(g[0][1]) * c0 + sig_(g[0][0]) * tanh_(g[0][2]);
        float cn1 = sig_(g[1][1]) * c1 + sig_(g[1][0]) * tanh_(g[1][2]);
        c0 = cn0; c1 = cn1;
        u32 hw = (u32)f2bf(sig_(g[0][3]) * tanh_(cn0))
               | ((u32)f2bf(sig_(g[1][3]) * tanh_(cn1)) << 16);
        __hip_atomic_store(Hw + ((u32)(s * 64 + jblk) * 64 + bb) * 4 + p, hw,
                           __ATOMIC_RELAXED, __HIP_MEMORY_SCOPE_AGENT);

        // ---- per-wave drain + flag publish (no second barrier) ----
        asm volatile("s_waitcnt vmcnt(0)" ::: "memory");
        if (l == 0)
            __hip_atomic_store(myflag, (u32)(step + 1),
                               __ATOMIC_RELAXED, __HIP_MEMORY_SCOPE_AGENT);
    }
}

// ---------- emissions: one block per s; rows b=0..63 ----------
__global__ void emis_kernel(const u16* __restrict__ hall, const u16* __restrict__ woutbf,
                            const float* __restrict__ bout, float* __restrict__ emis) {
    const int blk = blockIdx.x;                   // = s, 512 blocks
    const int t = threadIdx.x;
    const int w = t >> 6, l = t & 63;
    const int l16 = l & 15, lhi = l >> 4;
    const int b = w * 16 + l16;

    const u16* hf = hall + (size_t)blk * (64 * 64 * 8);   // dir 0, step blk
    const u16* hbk = hf + HB;                              // dir 1
    const u16* br0 = woutbf + (size_t)(0 * 16 + l16) * KC;
    const u16* br1 = woutbf + (size_t)(1 * 16 + l16) * KC;
    const u16* br2 = woutbf + (size_t)(2 * 16 + l16) * KC;
    const u16* br3 = woutbf + (size_t)(3 * 16 + l16) * KC;

    f32x4 a0 = {0.f,0.f,0.f,0.f}, a1 = {0.f,0.f,0.f,0.f}, a2 = {0.f,0.f,0.f,0.f}, a3 = {0.f,0.f,0.f,0.f};
#pragma unroll
    for (int kt = 0; kt < 16; ++kt) {             // h_f part
        int k = kt * 32 + lhi * 8;
        bf16x8 a = *reinterpret_cast<const bf16x8*>(hf + ((size_t)(k >> 3) * 64 + b) * 8);
        a0 = __builtin_amdgcn_mfma_f32_16x16x32_bf16(a, *reinterpret_cast<const bf16x8*>(br0 + k), a0, 0, 0, 0);
        a1 = __builtin_amdgcn_mfma_f32_16x16x32_bf16(a, *reinterpret_cast<const bf16x8*>(br1 + k), a1, 0, 0, 0);
        a2 = __builtin_amdgcn_mfma_f32_16x16x32_bf16(a, *reinterpret_cast<const bf16x8*>(br2 + k), a2, 0, 0, 0);
        a3 = __builtin_amdgcn_mfma_f32_16x16x32_bf16(a, *reinterpret_cast<const bf16x8*>(br3 + k), a3, 0, 0, 0);
    }
#pragma unroll
    for (int kt = 0; kt < 16; ++kt) {             // h_b part
        int k = kt * 32 + lhi * 8;
        bf16x8 a = *reinterpret_cast<const bf16x8*>(hbk + ((size_t)(k >> 3) * 64 + b) * 8);
        a0 = __builtin_amdgcn_mfma_f32_16x16x32_bf16(a, *reinterpret_cast<const bf16x8*>(br0 + NH + k), a0, 0, 0, 0);
        a1 = __builtin_amdgcn_mfma_f32_16x16x32_bf16(a, *reinterpret_cast<const bf16x8*>(br1 + NH + k), a1, 0, 0, 0);
        a2 = __builtin_amdgcn_mfma_f32_16x16x32_bf16(a, *reinterpret_cast<const bf16x8*>(br2 + NH + k), a2, 0, 0, 0);
        a3 = __builtin_amdgcn_mfma_f32_16x16x32_bf16(a, *reinterpret_cast<const bf16x8*>(br3 + NH + k), a3, 0, 0, 0);
    }
#pragma unroll
    for (int r = 0; r < 4; ++r) {
        int gm = blk * 64 + w * 16 + lhi * 4 + r;
        emis[(size_t)gm * NT + 0 * 16 + l16] = a0[r] + bout[0 * 16 + l16];
        emis[(size_t)gm * NT + 1 * 16 + l16] = a1[r] + bout[1 * 16 + l16];
        emis[(size_t)gm * NT + 2 * 16 + l16] = a2[r] + bout[2 * 16 + l16];
        emis[(size_t)gm * NT + 3 * 16 + l16] = a3[r] + bout[3 * 16 + l16];
    }
}

// ---------- gold score per batch ----------
__global__ void gold_kernel(const float* __restrict__ emis, const int* __restrict__ tags,
                            const float* __restrict__ trans, float* __restrict__ gold) {
    int b = blockIdx.x, t = threadIdx.x;
    float acc = 0.f;
    for (int s = t; s < NS; s += 256) {
        int tag = tags[b * NS + s];
        int prev = (s == 0) ? 0 : tags[b * NS + s - 1];
        acc += emis[(size_t)(s * NB + b) * NT + tag] + trans[tag * NT + prev];
    }
    acc += __shfl_xor(acc, 1);  acc += __shfl_xor(acc, 2);  acc += __shfl_xor(acc, 4);
    acc += __shfl_xor(acc, 8);  acc += __shfl_xor(acc, 16); acc += __shfl_xor(acc, 32);
    __shared__ float red[4];
    if ((t & 63) == 0) red[t >> 6] = acc;
    __syncthreads();
    if (t == 0) gold[b] = red[0] + red[1] + red[2] + red[3];
}

// ---------- CRF forward (log partition) per batch ----------
__global__ void crf_kernel(const float* __restrict__ emis, const float* __restrict__ trans,
                           float* __restrict__ fwd) {
    int b = blockIdx.x, t = threadIdx.x;
    __shared__ float transT[64][65];   // [prev][next]
    __shared__ float alA[64], alB[64];
    for (int idx = t; idx < 4096; idx += 256) {
        int next = idx & 63, prev = idx >> 6;
        transT[prev][next] = trans[next * NT + prev];
    }
    if (t < 64) alA[t] = (t == 0) ? 0.f : NEGV;
    __syncthreads();

    int next = t >> 2, q = t & 3;
    float* cur = alA;
    float* nxt = alB;
    for (int s = 0; s < NS; ++s) {
        float emit = emis[(size_t)(s * NB + b) * NT + next];
        int p0 = q * 16;
        float M = -3.0e38f;
#pragma unroll
        for (int i = 0; i < 16; ++i) {
            float v = cur[p0 + i] + transT[p0 + i][next];
            M = fmaxf(M, v);
        }
        M = fmaxf(M, __shfl_xor(M, 1));
        M = fmaxf(M, __shfl_xor(M, 2));
        float Ssum = 0.f;
#pragma unroll
        for (int i = 0; i < 16; ++i) {
            float v = cur[p0 + i] + transT[p0 + i][next];
            Ssum += expf(v - M);
        }
        Ssum += __shfl_xor(Ssum, 1);
        Ssum += __shfl_xor(Ssum, 2);
        if (q == 0) nxt[next] = M + logf(Ssum) + emit;
        __syncthreads();
        float* tmp = cur; cur = nxt; nxt = tmp;
    }
    if (t < 64) {
        float v = cur[t];
        float M = v;
        for (int d = 1; d < 64; d <<= 1) M = fmaxf(M, __shfl_xor(M, d));
        float e = expf(v - M);
        for (int d = 1; d < 64; d <<= 1) e += __shfl_xor(e, d);
        if (t == 0) fwd[b] = M + logf(e);
    }
}

// ---------- final: mean(fwd - gold) ----------
__global__ void final_kernel(const float* __restrict__ fwd, const float* __restrict__ gold,
                             float* __restrict__ out) {
    int t = threadIdx.x;   // 64
    float v = fwd[t] - gold[t];
    for (int d = 1; d < 64; d <<= 1) v += __shfl_xor(v, d);
    if (t == 0) out[0] = v * (1.0f / 64.0f);
}

extern "C" void kernel_launch(void* const* d_in, const int* in_sizes, int n_in,
                              void* d_out, int out_size, void* d_ws, size_t ws_size,
                              hipStream_t stream) {
    (void)in_sizes; (void)n_in; (void)out_size; (void)ws_size;
    const int* sents = (const int*)d_in[0];
    const int* tags  = (const int*)d_in[1];
    const float* emb  = (const float*)d_in[3];
    const float* wihf = (const float*)d_in[4];
    const float* whhf = (const float*)d_in[5];
    const float* bihf = (const float*)d_in[6];
    const float* bhhf = (const float*)d_in[7];
    const float* wihb = (const float*)d_in[8];
    const float* whhb = (const float*)d_in[9];
    const float* bihb = (const float*)d_in[10];
    const float* bhhb = (const float*)d_in[11];
    const float* wout = (const float*)d_in[12];
    const float* bout = (const float*)d_in[13];
    const float* trans = (const float*)d_in[14];

    char* ws = (char*)d_ws;
    u16*   WCOMB  = (u16*)(ws + 0);              //  8 MiB  [2][2048][1024] bf16
    u16*   WOUTBF = (u16*)(ws + 8388608);        //  128 KiB [64][1024] bf16
    float* BIAS   = (float*)(ws + 8519680);      //  16 KiB  [2][2048] f32
    u32*   FLAGS  = (u32*)(ws + 8536064);        //  2 KiB   [2][256] u32
    u16*   XBF    = (u16*)(ws + 8544256);        //  32 MiB  [32768][512] bf16
    u16*   HALL   = (u16*)(ws + 42098688);       //  64 MiB  [2][512][64][64][8] bf16
    float* EMIS   = (float*)(ws + 109207552);    //  8 MiB   [512*64][64] f32
    float* FWD    = (float*)(ws + 117596160);    //  [64] f32
    float* GOLD   = (float*)(ws + 117596416);    //  [64] f32

    prep_wcomb<<<4096, 256, 0, stream>>>(wihf, whhf, wihb, whhb, WCOMB);
    prep_misc<<<274, 256, 0, stream>>>(wout, bihf, bhhf, bihb, bhhb, WOUTBF, BIAS, FLAGS);
    prep_embed<<<16384, 256, 0, stream>>>(emb, sents, XBF);

    lstm_persist<<<dim3(64, 2), 256, 0, stream>>>(XBF, WCOMB, BIAS, HALL, FLAGS);

    emis_kernel<<<512, 256, 0, stream>>>(HALL, WOUTBF, bout, EMIS);
    gold_kernel<<<64, 256, 0, stream>>>(EMIS, tags, trans, GOLD);
    crf_kernel<<<64, 256, 0, stream>>>(EMIS, trans, FWD);
    final_kernel<<<1, 64, 0, stream>>>(FWD, GOLD, (float*)d_out);
}

// Round 7
// 4383.510 us; speedup vs baseline: 5.8459x; 1.0751x over previous
//
#include <hip/hip_runtime.h>

#define NB 64      // batch
#define NS 512     // seq len
#define NE 512     // emb dim
#define NH 512     // per-dir hidden
#define NG 2048    // 4*NH
#define NT 64      // tags
#define KC 1024    // combined K = NE + NH
#define HB 16777216   // u16 elements per direction in HALL
#define SENT32 0x7FC07FC0u  // bf16 NaN|NaN — unreachable for h = sig*tanh
#define NEGV (-10000.0f)

typedef __attribute__((ext_vector_type(8))) short bf16x8;
typedef __attribute__((ext_vector_type(4))) float f32x4;
typedef unsigned short u16;
typedef unsigned int u32;
typedef unsigned long long u64;

__device__ __forceinline__ u16 f2bf(float x) {
    unsigned u = __builtin_bit_cast(unsigned, x);
    u += 0x7fffu + ((u >> 16) & 1u);
    return (u16)(u >> 16);
}
__device__ __forceinline__ float sig_(float x) {
    return __builtin_amdgcn_rcpf(1.0f + __builtin_amdgcn_exp2f(-1.44269504f * x));
}
__device__ __forceinline__ float tanh_(float x) {
    return 2.0f * __builtin_amdgcn_rcpf(1.0f + __builtin_amdgcn_exp2f(-2.88539009f * x)) - 1.0f;
}

// ---------- prep: combined [W_ih | W_hh] -> bf16, [2][2048][1024] ----------
__global__ void prep_wcomb(const float* __restrict__ wihf, const float* __restrict__ whhf,
                           const float* __restrict__ wihb, const float* __restrict__ whhb,
                           u16* __restrict__ wcomb) {
    int idx = blockIdx.x * 256 + threadIdx.x;   // 1,048,576 threads, 4 elems each
    int base = idx * 4;
    int d = base >> 21;
    int rem = base & ((1 << 21) - 1);
    int n = rem >> 10;
    int k = rem & 1023;
    const float* wih = d ? wihb : wihf;
    const float* whh = d ? whhb : whhf;
    const float* src = (k < NE) ? (wih + n * NE + k) : (whh + n * NH + (k - NE));
    float4 v = *reinterpret_cast<const float4*>(src);
    ushort4 o;
    o.x = f2bf(v.x); o.y = f2bf(v.y); o.z = f2bf(v.z); o.w = f2bf(v.w);
    *reinterpret_cast<ushort4*>(wcomb + base) = o;
}

// ---------- prep: w_out->bf16, bias = b_ih+b_hh ----------
__global__ void prep_misc(const float* __restrict__ wout,
                          const float* __restrict__ bihf, const float* __restrict__ bhhf,
                          const float* __restrict__ bihb, const float* __restrict__ bhhb,
                          u16* __restrict__ woutbf, float* __restrict__ bias) {
    int idx = blockIdx.x * 256 + threadIdx.x;   // 272 blocks = 69,632 threads
    if (idx < 65536) { woutbf[idx] = f2bf(wout[idx]); return; }
    idx -= 65536;
    if (idx < 4096) {
        int d = idx >> 11, g = idx & 2047;
        bias[idx] = d ? (bihb[g] + bhhb[g]) : (bihf[g] + bhhf[g]);
    }
}

// ---------- prep: sentinel-fill HALL (64 MiB) ----------
__global__ void prep_hfill(uint4* __restrict__ h) {
    int idx = blockIdx.x * 256 + threadIdx.x;   // 16384 blocks
    uint4 v = {SENT32, SENT32, SENT32, SENT32};
    h[idx] = v;
}

// ---------- prep: embedding gather -> x_bf[(s*64+b)][512] bf16 ----------
__global__ void prep_embed(const float* __restrict__ emb, const int* __restrict__ sents,
                           u16* __restrict__ xbf) {
    int idx = blockIdx.x * 256 + threadIdx.x;   // 4,194,304 threads, 4 elems each
    int m = idx >> 7;
    int e = (idx & 127) << 2;
    int s = m >> 6, b = m & 63;
    int tok = sents[b * NS + s];
    float4 v = *reinterpret_cast<const float4*>(emb + (size_t)tok * NE + e);
    ushort4 o;
    o.x = f2bf(v.x); o.y = f2bf(v.y); o.z = f2bf(v.z); o.w = f2bf(v.w);
    *reinterpret_cast<ushort4*>(xbf + (size_t)m * NE + e) = o;
}

// ---------- persistent bi-LSTM: grid (32 jblk, 2 dir), 512 thr, 8 waves ----------
// HALL per dir: row-major h[s][b][j] bf16. Producers fire-and-forget relaxed
// agent stores (no drain, no flags). Consumers load the 32 fragments they
// need ONCE, sentinel-validate per fragment, and retry ONLY the invalid
// fragments (narrow retries, s_sleep backoff) — a single wait point per step.
// Wave w: K-slice 128*w (w 0-3: x-part, never waits; w 4-7: h-part).
// All 64 gate-cols per wave (nf 0..3 == gate index). Weights in registers.
__global__ __launch_bounds__(512, 1)
void lstm_persist(const u16* __restrict__ xbf, const u16* __restrict__ wcomb,
                  const float* __restrict__ bias, u16* __restrict__ hall) {
    const int jblk = blockIdx.x;   // 0..31 -> j slice of 16
    const int dir  = blockIdx.y;   // 0 fwd, 1 bwd
    const int t = threadIdx.x;
    const int w = t >> 6, l = t & 63;
    const int l16 = l & 15, lhi = l >> 4;
    const int kbase = w * 128;
    const bool isx = (w < 4);

    __shared__ float gred[8][64][68];   // 139 KiB partial-gate buffer

    // ---- B-fragments in registers (once): 4 gates x 4 k-tiles = 64 VGPR ----
    bf16x8 bfrag[4][4];
#pragma unroll
    for (int nf = 0; nf < 4; ++nf)
#pragma unroll
        for (int kt = 0; kt < 4; ++kt) {
            int gr = nf * NH + jblk * 16 + l16;          // gate nf, j-col l16
            int k = kbase + kt * 32 + lhi * 8;
            bfrag[nf][kt] = *reinterpret_cast<const bf16x8*>(
                wcomb + (size_t)(dir * NG + gr) * KC + k);
        }

    // ---- epilogue ownership: thread -> (bb = t>>3, jo = t&7 -> j0 = 2*jo) ----
    const int bb = t >> 3;
    const int jo = t & 7;
    const int j0 = jo * 2;
    float breg[4][2];
#pragma unroll
    for (int gi = 0; gi < 4; ++gi)
#pragma unroll
        for (int u = 0; u < 2; ++u)
            breg[gi][u] = bias[dir * NG + gi * NH + jblk * 16 + j0 + u];
    float c0 = 0.f, c1 = 0.f;   // cell state in registers

    u32* Hw = reinterpret_cast<u32*>(hall) + (size_t)dir * (HB / 2);
    const u64* Hq = reinterpret_cast<const u64*>(hall) + (size_t)dir * (HB / 4);

    for (int step = 0; step < NS; ++step) {
        const int s = dir ? (NS - 1 - step) : step;
        const int sprev = dir ? (s + 1) : (s - 1);

        f32x4 acc[4][4];
#pragma unroll
        for (int mf = 0; mf < 4; ++mf)
#pragma unroll
            for (int nf = 0; nf < 4; ++nf)
                acc[mf][nf] = (f32x4){0.f, 0.f, 0.f, 0.f};

        if (isx) {
            // x part: no cross-block dependency -> never waits
            const u16* Abase = xbf + (size_t)(s * NB) * NE + kbase;
#pragma unroll
            for (int kt = 0; kt < 4; ++kt) {
                int k = kt * 32 + lhi * 8;
#pragma unroll
                for (int mf = 0; mf < 4; ++mf) {
                    bf16x8 a = *reinterpret_cast<const bf16x8*>(Abase + (size_t)(mf * 16 + l16) * NE + k);
#pragma unroll
                    for (int nf = 0; nf < 4; ++nf)
                        acc[mf][nf] = __builtin_amdgcn_mfma_f32_16x16x32_bf16(a, bfrag[nf][kt], acc[mf][nf], 0, 0, 0);
                }
            }
        } else if (step > 0) {
            const int kloc = kbase - 512;
            // ---- load all 16 fragments once; validate; narrow retries ----
            u64 qa[4][4], qb[4][4];
            u32 okm = 0;
#pragma unroll
            for (int kt = 0; kt < 4; ++kt) {
                int j = kloc + kt * 32 + lhi * 8;
#pragma unroll
                for (int mf = 0; mf < 4; ++mf) {
                    const u64* P = Hq + (size_t)(sprev * NB + mf * 16 + l16) * 128 + (j >> 2);
                    u64 v0 = __hip_atomic_load(P,     __ATOMIC_RELAXED, __HIP_MEMORY_SCOPE_AGENT);
                    u64 v1 = __hip_atomic_load(P + 1, __ATOMIC_RELAXED, __HIP_MEMORY_SCOPE_AGENT);
                    qa[kt][mf] = v0; qb[kt][mf] = v1;
                    bool bad = ((u32)v0 == SENT32) | ((u32)(v0 >> 32) == SENT32)
                             | ((u32)v1 == SENT32) | ((u32)(v1 >> 32) == SENT32);
                    okm |= (bad ? 0u : 1u) << (kt * 4 + mf);
                }
            }
            while (__ballot(okm != 0xFFFFu)) {
                __builtin_amdgcn_s_sleep(1);
#pragma unroll
                for (int kt = 0; kt < 4; ++kt) {
                    int j = kloc + kt * 32 + lhi * 8;
#pragma unroll
                    for (int mf = 0; mf < 4; ++mf) {
                        u32 bit = 1u << (kt * 4 + mf);
                        if (!(okm & bit)) {
                            const u64* P = Hq + (size_t)(sprev * NB + mf * 16 + l16) * 128 + (j >> 2);
                            u64 v0 = __hip_atomic_load(P,     __ATOMIC_RELAXED, __HIP_MEMORY_SCOPE_AGENT);
                            u64 v1 = __hip_atomic_load(P + 1, __ATOMIC_RELAXED, __HIP_MEMORY_SCOPE_AGENT);
                            qa[kt][mf] = v0; qb[kt][mf] = v1;
                            bool bad = ((u32)v0 == SENT32) | ((u32)(v0 >> 32) == SENT32)
                                     | ((u32)v1 == SENT32) | ((u32)(v1 >> 32) == SENT32);
                            if (!bad) okm |= bit;
                        }
                    }
                }
            }
            __builtin_amdgcn_sched_barrier(0);
#pragma unroll
            for (int kt = 0; kt < 4; ++kt) {
#pragma unroll
                for (int mf = 0; mf < 4; ++mf) {
                    union { u64 q[2]; bf16x8 v; } cv;
                    cv.q[0] = qa[kt][mf]; cv.q[1] = qb[kt][mf];
#pragma unroll
                    for (int nf = 0; nf < 4; ++nf)
                        acc[mf][nf] = __builtin_amdgcn_mfma_f32_16x16x32_bf16(cv.v, bfrag[nf][kt], acc[mf][nf], 0, 0, 0);
                }
            }
        }

        // ---- dump partials ----
#pragma unroll
        for (int mf = 0; mf < 4; ++mf)
#pragma unroll
            for (int nf = 0; nf < 4; ++nf)
#pragma unroll
                for (int r = 0; r < 4; ++r)
                    gred[w][mf * 16 + lhi * 4 + r][nf * 16 + l16] = acc[mf][nf][r];
        __syncthreads();

        // ---- reduce 8 K-partials + cell update (c in regs), 2 cells/thread ----
        float g[2][4];
#pragma unroll
        for (int u = 0; u < 2; ++u)
#pragma unroll
            for (int gi = 0; gi < 4; ++gi) {
                int n = gi * 16 + j0 + u;
                float sum = gred[0][bb][n];
#pragma unroll
                for (int kw = 1; kw < 8; ++kw) sum += gred[kw][bb][n];
                g[u][gi] = sum + breg[gi][u];
            }
        float cn0 = sig_(g[0][1]) * c0 + sig_(g[0][0]) * tanh_(g[0][2]);
        float cn1 = sig_(g[1][1]) * c1 + sig_(g[1][0]) * tanh_(g[1][2]);
        c0 = cn0; c1 = cn1;
        u32 hw = (u32)f2bf(sig_(g[0][3]) * tanh_(cn0))
               | ((u32)f2bf(sig_(g[1][3]) * tanh_(cn1)) << 16);
        // fire-and-forget publish: h[s][bb][jblk*16 + j0..j0+1]
        __hip_atomic_store(Hw + (size_t)(s * NB + bb) * 256 + jblk * 8 + jo, hw,
                           __ATOMIC_RELAXED, __HIP_MEMORY_SCOPE_AGENT);
        __syncthreads();   // gred reuse protection for next step
    }
}

// ---------- emissions: one block per s; rows b=0..63 ----------
__global__ void emis_kernel(const u16* __restrict__ hall, const u16* __restrict__ woutbf,
                            const float* __restrict__ bout, float* __restrict__ emis) {
    const int blk = blockIdx.x;                   // = s, 512 blocks
    const int t = threadIdx.x;
    const int w = t >> 6, l = t & 63;
    const int l16 = l & 15, lhi = l >> 4;

    const u16* arow0 = hall + (size_t)(blk * 64 + w * 16 + l16) * NH;
    const u16* arow1 = arow0 + HB;
    const u16* br0 = woutbf + (size_t)(0 * 16 + l16) * KC;
    const u16* br1 = woutbf + (size_t)(1 * 16 + l16) * KC;
    const u16* br2 = woutbf + (size_t)(2 * 16 + l16) * KC;
    const u16* br3 = woutbf + (size_t)(3 * 16 + l16) * KC;

    f32x4 a0 = {0.f,0.f,0.f,0.f}, a1 = {0.f,0.f,0.f,0.f}, a2 = {0.f,0.f,0.f,0.f}, a3 = {0.f,0.f,0.f,0.f};
#pragma unroll
    for (int kt = 0; kt < 16; ++kt) {             // h_f part
        int k = kt * 32 + lhi * 8;
        bf16x8 a = *reinterpret_cast<const bf16x8*>(arow0 + k);
        a0 = __builtin_amdgcn_mfma_f32_16x16x32_bf16(a, *reinterpret_cast<const bf16x8*>(br0 + k), a0, 0, 0, 0);
        a1 = __builtin_amdgcn_mfma_f32_16x16x32_bf16(a, *reinterpret_cast<const bf16x8*>(br1 + k), a1, 0, 0, 0);
        a2 = __builtin_amdgcn_mfma_f32_16x16x32_bf16(a, *reinterpret_cast<const bf16x8*>(br2 + k), a2, 0, 0, 0);
        a3 = __builtin_amdgcn_mfma_f32_16x16x32_bf16(a, *reinterpret_cast<const bf16x8*>(br3 + k), a3, 0, 0, 0);
    }
#pragma unroll
    for (int kt = 0; kt < 16; ++kt) {             // h_b part
        int k = kt * 32 + lhi * 8;
        bf16x8 a = *reinterpret_cast<const bf16x8*>(arow1 + k);
        a0 = __builtin_amdgcn_mfma_f32_16x16x32_bf16(a, *reinterpret_cast<const bf16x8*>(br0 + NH + k), a0, 0, 0, 0);
        a1 = __builtin_amdgcn_mfma_f32_16x16x32_bf16(a, *reinterpret_cast<const bf16x8*>(br1 + NH + k), a1, 0, 0, 0);
        a2 = __builtin_amdgcn_mfma_f32_16x16x32_bf16(a, *reinterpret_cast<const bf16x8*>(br2 + NH + k), a2, 0, 0, 0);
        a3 = __builtin_amdgcn_mfma_f32_16x16x32_bf16(a, *reinterpret_cast<const bf16x8*>(br3 + NH + k), a3, 0, 0, 0);
    }
#pragma unroll
    for (int r = 0; r < 4; ++r) {
        int gm = blk * 64 + w * 16 + lhi * 4 + r;
        emis[(size_t)gm * NT + 0 * 16 + l16] = a0[r] + bout[0 * 16 + l16];
        emis[(size_t)gm * NT + 1 * 16 + l16] = a1[r] + bout[1 * 16 + l16];
        emis[(size_t)gm * NT + 2 * 16 + l16] = a2[r] + bout[2 * 16 + l16];
        emis[(size_t)gm * NT + 3 * 16 + l16] = a3[r] + bout[3 * 16 + l16];
    }
}

// ---------- gold score per batch ----------
__global__ void gold_kernel(const float* __restrict__ emis, const int* __restrict__ tags,
                            const float* __restrict__ trans, float* __restrict__ gold) {
    int b = blockIdx.x, t = threadIdx.x;
    float acc = 0.f;
    for (int s = t; s < NS; s += 256) {
        int tag = tags[b * NS + s];
        int prev = (s == 0) ? 0 : tags[b * NS + s - 1];
        acc += emis[(size_t)(s * NB + b) * NT + tag] + trans[tag * NT + prev];
    }
    acc += __shfl_xor(acc, 1);  acc += __shfl_xor(acc, 2);  acc += __shfl_xor(acc, 4);
    acc += __shfl_xor(acc, 8);  acc += __shfl_xor(acc, 16); acc += __shfl_xor(acc, 32);
    __shared__ float red[4];
    if ((t & 63) == 0) red[t >> 6] = acc;
    __syncthreads();
    if (t == 0) gold[b] = red[0] + red[1] + red[2] + red[3];
}

// ---------- CRF forward (log partition) per batch ----------
__global__ void crf_kernel(const float* __restrict__ emis, const float* __restrict__ trans,
                           float* __restrict__ fwd) {
    int b = blockIdx.x, t = threadIdx.x;
    __shared__ float transT[64][65];   // [prev][next]
    __shared__ float alA[64], alB[64];
    for (int idx = t; idx < 4096; idx += 256) {
        int next = idx & 63, prev = idx >> 6;
        transT[prev][next] = trans[next * NT + prev];
    }
    if (t < 64) alA[t] = (t == 0) ? 0.f : NEGV;
    __syncthreads();

    int next = t >> 2, q = t & 3;
    float* cur = alA;
    float* nxt = alB;
    for (int s = 0; s < NS; ++s) {
        float emit = emis[(size_t)(s * NB + b) * NT + next];
        int p0 = q * 16;
        float M = -3.0e38f;
#pragma unroll
        for (int i = 0; i < 16; ++i) {
            float v = cur[p0 + i] + transT[p0 + i][next];
            M = fmaxf(M, v);
        }
        M = fmaxf(M, __shfl_xor(M, 1));
        M = fmaxf(M, __shfl_xor(M, 2));
        float Ssum = 0.f;
#pragma unroll
        for (int i = 0; i < 16; ++i) {
            float v = cur[p0 + i] + transT[p0 + i][next];
            Ssum += expf(v - M);
        }
        Ssum += __shfl_xor(Ssum, 1);
        Ssum += __shfl_xor(Ssum, 2);
        if (q == 0) nxt[next] = M + logf(Ssum) + emit;
        __syncthreads();
        float* tmp = cur; cur = nxt; nxt = tmp;
    }
    if (t < 64) {
        float v = cur[t];
        float M = v;
        for (int d = 1; d < 64; d <<= 1) M = fmaxf(M, __shfl_xor(M, d));
        float e = expf(v - M);
        for (int d = 1; d < 64; d <<= 1) e += __shfl_xor(e, d);
        if (t == 0) fwd[b] = M + logf(e);
    }
}

// ---------- final: mean(fwd - gold) ----------
__global__ void final_kernel(const float* __restrict__ fwd, const float* __restrict__ gold,
                             float* __restrict__ out) {
    int t = threadIdx.x;   // 64
    float v = fwd[t] - gold[t];
    for (int d = 1; d < 64; d <<= 1) v += __shfl_xor(v, d);
    if (t == 0) out[0] = v * (1.0f / 64.0f);
}

extern "C" void kernel_launch(void* const* d_in, const int* in_sizes, int n_in,
                              void* d_out, int out_size, void* d_ws, size_t ws_size,
                              hipStream_t stream) {
    (void)in_sizes; (void)n_in; (void)out_size; (void)ws_size;
    const int* sents = (const int*)d_in[0];
    const int* tags  = (const int*)d_in[1];
    const float* emb  = (const float*)d_in[3];
    const float* wihf = (const float*)d_in[4];
    const float* whhf = (const float*)d_in[5];
    const float* bihf = (const float*)d_in[6];
    const float* bhhf = (const float*)d_in[7];
    const float* wihb = (const float*)d_in[8];
    const float* whhb = (const float*)d_in[9];
    const float* bihb = (const float*)d_in[10];
    const float* bhhb = (const float*)d_in[11];
    const float* wout = (const float*)d_in[12];
    const float* bout = (const float*)d_in[13];
    const float* trans = (const float*)d_in[14];

    char* ws = (char*)d_ws;
    u16*   WCOMB  = (u16*)(ws + 0);              //  8 MiB  [2][2048][1024] bf16
    u16*   WOUTBF = (u16*)(ws + 8388608);        //  128 KiB [64][1024] bf16
    float* BIAS   = (float*)(ws + 8519680);      //  16 KiB  [2][2048] f32
    u16*   XBF    = (u16*)(ws + 8536064);        //  32 MiB  [32768][512] bf16
    u16*   HALL   = (u16*)(ws + 42090496);       //  64 MiB  [2][512][64][512] bf16
    float* EMIS   = (float*)(ws + 109199360);    //  8 MiB   [512*64][64] f32
    float* FWD    = (float*)(ws + 117587968);    //  [64] f32
    float* GOLD   = (float*)(ws + 117588224);    //  [64] f32

    prep_wcomb<<<4096, 256, 0, stream>>>(wihf, whhf, wihb, whhb, WCOMB);
    prep_misc<<<272, 256, 0, stream>>>(wout, bihf, bhhf, bihb, bhhb, WOUTBF, BIAS);
    prep_hfill<<<16384, 256, 0, stream>>>((uint4*)HALL);
    prep_embed<<<16384, 256, 0, stream>>>(emb, sents, XBF);

    lstm_persist<<<dim3(32, 2), 512, 0, stream>>>(XBF, WCOMB, BIAS, HALL);

    emis_kernel<<<512, 256, 0, stream>>>(HALL, WOUTBF, bout, EMIS);
    gold_kernel<<<64, 256, 0, stream>>>(EMIS, tags, trans, GOLD);
    crf_kernel<<<64, 256, 0, stream>>>(EMIS, trans, FWD);
    final_kernel<<<1, 64, 0, stream>>>(FWD, GOLD, (float*)d_out);
}